// Round 7
// baseline (558.874 us; speedup 1.0000x reference)
//
#include <hip/hip_runtime.h>

// WeightedFusionLayer: B=65536, S=49, C=19, fp32.
//   alpha = softmax(Hf @ Wa); beta = softmax(Hh @ Wb)   (per (b,s) row, over C)
//   out[b] = sigmoid( sum_{s,c} (alpha*Hf + beta*Hh) * Wout[s,c] + bias )
//
// R6: R3 was latency-stalled (VALUBusy 48%, occ 85%, VGPR starved at 32).
// Fixes: single up-front staging of Hf+Hh+Wo with ONE sync; h/wo cached in
// VGPRs (pure-register inner loops, no vector-mem in hot path);
// launch_bounds(64,6) -> 84-VGPR cap so the allocator isn't starved.

#define BB    65536
#define S     49
#define C     19
#define NPAIR (BB * S)          // 3,211,264
#define PPB   64                // 1 wave per block
#define NBLK  (NPAIR / PPB)     // 50,176

__global__ __launch_bounds__(PPB, 6)
void wfl_main(const float* __restrict__ Hf, const float* __restrict__ Hh,
              const float* __restrict__ Wa, const float* __restrict__ Wb,
              const float* __restrict__ Wo, float* __restrict__ ws)
{
    __shared__ __align__(16) float lhf[PPB * C];   // 4864 B
    __shared__ __align__(16) float lhh[PPB * C];   // 4864 B
    __shared__ __align__(16) float lwo[936];       // 3744 B (931 used + pad)

    const int lane = threadIdx.x;
    const int blk  = blockIdx.x;
    const int p0   = blk * PPB;
    const int p    = p0 + lane;
    const int b    = p / S;                        // magic-mul
    const int s    = p - b * S;

    // ---- stage everything up-front, one sync ----
    {
        const float4* gf = (const float4*)(Hf + (size_t)p0 * C);   // blk*4864B, 16B aligned
        const float4* gh = (const float4*)(Hh + (size_t)p0 * C);
        const float4* gw = (const float4*)Wo;
        float4* sf = (float4*)lhf;
        float4* sh = (float4*)lhh;
        float4* sw = (float4*)lwo;
#pragma unroll
        for (int k = 0; k < 5; ++k) {
            int i = lane + k * PPB;
            if (i < 304) { sf[i] = gf[i]; sh[i] = gh[i]; }         // 304 float4 each, exact
        }
#pragma unroll
        for (int k = 0; k < 4; ++k) {
            int i = lane + k * PPB;
            if (i < 232) sw[i] = gw[i];                            // floats 0..927
        }
        if (lane < 3) lwo[928 + lane] = Wo[928 + lane];            // exact in-bounds tail
    }
    __syncthreads();

    // ---- per-pair constants into registers ----
    float wo[C];
#pragma unroll
    for (int c = 0; c < C; ++c) wo[c] = lwo[s * C + c];            // <=3-way bank alias

    float part = 0.f;

    // ---------------- phase A: alpha gate (H_factor, W_alpha) ----------------
    {
        float h[C];
#pragma unroll
        for (int c = 0; c < C; ++c) h[c] = lhf[lane * C + c];      // cached once

        float l[C];
#pragma unroll
        for (int d = 0; d < C; ++d) l[d] = 0.f;
#pragma unroll
        for (int c = 0; c < C; ++c) {
            const float hc = h[c];
#pragma unroll
            for (int d = 0; d < C; ++d)
                l[d] = fmaf(hc, Wa[c * C + d], l[d]);              // s_load + v_fmac v,s,v
        }
        float den = 0.f, num = 0.f;
#pragma unroll
        for (int d = 0; d < C; ++d) {
            const float e = __expf(l[d]);                          // no max-sub (logit sigma~4.4)
            den += e;
            num = fmaf(e, h[d] * wo[d], num);                      // pure register math
        }
        part = fmaf(num, __builtin_amdgcn_rcpf(den), part);
    }

    // ---------------- phase B: beta gate (H_hybrid, W_beta) ----------------
    {
        float h[C];
#pragma unroll
        for (int c = 0; c < C; ++c) h[c] = lhh[lane * C + c];      // hf regs now dead

        float l[C];
#pragma unroll
        for (int d = 0; d < C; ++d) l[d] = 0.f;
#pragma unroll
        for (int c = 0; c < C; ++c) {
            const float hc = h[c];
#pragma unroll
            for (int d = 0; d < C; ++d)
                l[d] = fmaf(hc, Wb[c * C + d], l[d]);
        }
        float den = 0.f, num = 0.f;
#pragma unroll
        for (int d = 0; d < C; ++d) {
            const float e = __expf(l[d]);
            den += e;
            num = fmaf(e, h[d] * wo[d], num);
        }
        part = fmaf(num, __builtin_amdgcn_rcpf(den), part);
    }

    // -------- segmented reduction over <=3 batches in this wave + atomic ----
    const int b0 = p0 / S;
#pragma unroll
    for (int k = 0; k < 3; ++k) {
        float v = ((b - b0) == k) ? part : 0.f;
#pragma unroll
        for (int off = 32; off; off >>= 1) v += __shfl_xor(v, off, 64);
        if (lane == 0 && (b0 + k) < BB) unsafeAtomicAdd(&ws[b0 + k], v);
    }
}

__global__ __launch_bounds__(256)
void wfl_fin(const float* __restrict__ ws, const float* __restrict__ bias,
             float* __restrict__ out)
{
    const int i = blockIdx.x * 256 + threadIdx.x;   // 65536 total
    const float u = ws[i] + bias[0];
    out[i] = __builtin_amdgcn_rcpf(1.f + __expf(-u));
}

extern "C" void kernel_launch(void* const* d_in, const int* in_sizes, int n_in,
                              void* d_out, int out_size, void* d_ws, size_t ws_size,
                              hipStream_t stream)
{
    const float* Hf   = (const float*)d_in[0];
    const float* Hh   = (const float*)d_in[1];
    const float* Wa   = (const float*)d_in[2];
    const float* Wb   = (const float*)d_in[3];
    const float* Wo   = (const float*)d_in[4];
    const float* bias = (const float*)d_in[5];
    float* out = (float*)d_out;
    float* acc = (float*)d_ws;                      // 65536 floats = 256 KB

    hipMemsetAsync(acc, 0, BB * sizeof(float), stream);   // ws is re-poisoned each call
    wfl_main<<<NBLK, PPB, 0, stream>>>(Hf, Hh, Wa, Wb, Wo, acc);
    wfl_fin<<<BB / 256, 256, 0, stream>>>(acc, bias, out);
}